// Round 1
// 335.199 us; speedup vs baseline: 1.0512x; 1.0512x over previous
//
#include <hip/hip_runtime.h>
#include <hip/hip_bf16.h>
#include <stdint.h>

// Problem constants
#define B_   16
#define H_   112
#define W_   112
#define CIN  128
#define F_   256
#define OH   110
#define OW   110
#define MTOT (B_*OH*OW)        // 193600 output pixels
#define KTOT 1152              // 3*3*128
#define PIX_IN (B_*H_*W_)      // 200704 input pixels
#define D_INV (1.0f/1152.0f)

typedef float floatx4 __attribute__((ext_vector_type(4)));
typedef int   intx4   __attribute__((ext_vector_type(4)));

typedef __attribute__((address_space(1))) uint32_t guint;
typedef __attribute__((address_space(3))) uint32_t luint;

__device__ __forceinline__ void gld_lds16(const void* g, void* l) {
    __builtin_amdgcn_global_load_lds((guint*)g, (luint*)l, 16, 0, 0);
}

// ws layout (bytes):
//   wst  i8   [18 ks][2 fh][4 chunk][128 n][16 j]  = 294912
//   sf   f32  [256]                                = 1024
//   S    f32  [PIX_IN]                             = 802816
//   beta f32  [MTOT]                               = 774400
//   xq   i8   [PIX_IN*CIN]                         = 25690112
#define WST_OFF   0
#define SF_OFF    294912
#define S_OFF     295936
#define BETA_OFF  1098752
#define XQ_OFF    1873152
#define NEED_FULL (XQ_OFF + (size_t)PIX_IN*CIN)

// ---- prep: W' = sum_e alpha[e,f]*sign(K_e); quantize i8 with s_f ----------
__global__ void prep_wq(const float* __restrict__ kern, const float* __restrict__ alph,
                        int8_t* __restrict__ wst, float* __restrict__ sf) {
    int idx = blockIdx.x * 256 + threadIdx.x;   // = r*256 + f
    int r = idx >> 8, f = idx & 255;
    float a0 = alph[f], a1 = alph[256 + f], a2 = alph[512 + f];  // >= 0
    float w = 0.f;
    float kv0 = kern[idx], kv1 = kern[294912 + idx], kv2 = kern[589824 + idx];
    w += (__float_as_uint(kv0) & 0x80000000u) ? -a0 : a0;
    w += (__float_as_uint(kv1) & 0x80000000u) ? -a1 : a1;
    w += (__float_as_uint(kv2) & 0x80000000u) ? -a2 : a2;
    float s = (a0 + a1 + a2) * (1.0f / 127.0f);          // bounds |w| -> |q|<=127
    int q = (int)__builtin_rintf(w / s);
    // image addr: [ks=r>>6][fh=f>>7][chunk=(r>>4)&3][n=f&127][j=r&15]
    wst[((((r >> 6) * 2 + (f >> 7)) * 4 + ((r >> 4) & 3)) * 128 + (f & 127)) * 16 + (r & 15)]
        = (int8_t)q;
    if (r == 0) sf[f] = s;
}

// ---- prep: binarize x -> xq (i8 +-1), per-pixel sum|x| --------------------
__device__ __forceinline__ uint32_t pack4sign(float4 v) {
    uint32_t b0 = ((__float_as_uint(v.x) >> 31) * 0xFEu) ^ 0x01u;
    uint32_t b1 = ((__float_as_uint(v.y) >> 31) * 0xFEu) ^ 0x01u;
    uint32_t b2 = ((__float_as_uint(v.z) >> 31) * 0xFEu) ^ 0x01u;
    uint32_t b3 = ((__float_as_uint(v.w) >> 31) * 0xFEu) ^ 0x01u;
    return b0 | (b1 << 8) | (b2 << 16) | (b3 << 24);
}

__global__ void prep_x(const float* __restrict__ x, uint32_t* __restrict__ xq,
                       float* __restrict__ S, int write_xq) {
    int idx = blockIdx.x * 256 + threadIdx.x;   // float4 index; 32 per pixel
    float4 v = ((const float4*)x)[idx];
    if (write_xq) xq[idx] = pack4sign(v);
    float s = fabsf(v.x) + fabsf(v.y) + fabsf(v.z) + fabsf(v.w);
#pragma unroll
    for (int o = 1; o < 32; o <<= 1) s += __shfl_xor(s, o, 64);  // within 32-group
    if ((threadIdx.x & 31) == 0) S[idx >> 5] = s;
}

// ---- prep: beta = 3x3 box of S / 1152 -------------------------------------
__global__ void prep_beta(const float* __restrict__ S, float* __restrict__ beta) {
    int m = blockIdx.x * 256 + threadIdx.x;
    if (m >= MTOT) return;
    int b = m / (OH * OW); int r = m - b * (OH * OW);
    int oi = r / OW, oj = r - oi * OW;
    const float* sp = S + (b * H_ + oi) * W_ + oj;
    float acc = 0.f;
#pragma unroll
    for (int dh = 0; dh < 3; ++dh)
#pragma unroll
        for (int dw = 0; dw < 3; ++dw) acc += sp[dh * W_ + dw];
    beta[m] = acc * D_INV;
}

// ---- main: implicit GEMM, 128x128 tile, 16x16x64 i8 MFMA, BK=64 -----------
// v2: double-buffered LDS + 1-step prefetch with counted vmcnt(4),
//     bijective XCD-aware block swizzle, setprio around MFMA cluster.
template <bool PREBIN>
__global__ __launch_bounds__(256)
void conv_main(const void* __restrict__ xin, const int8_t* __restrict__ wst,
               const float* __restrict__ sf, const float* __restrict__ beta,
               float* __restrict__ out) {
    // two buffers of 16 KB: each {A: [4 chunk(k16)][128 row][16B]; B at +8192}
    __shared__ char smem[32768];

    const int t = threadIdx.x;
    const int l = t & 63, wv = t >> 6;
    const int quad = l >> 4, lane16 = l & 15;
    const int wm = wv >> 1, wn = wv & 1;

    // --- bijective XCD swizzle (m204): contiguous logical ids per XCD ---
    const int nwg  = gridDim.x * gridDim.y;            // 3026
    const int wgid = blockIdx.y * gridDim.x + blockIdx.x;
    const int qn = nwg >> 3, rn = nwg & 7;
    const int xcd = wgid & 7, ii = wgid >> 3;
    const int nid = (xcd < rn ? xcd * (qn + 1) : rn * (qn + 1) + (xcd - rn) * qn) + ii;
    const int f0 = (nid & 1) * 128;     // f-halves of same m-tile adjacent -> same XCD
    const int m0 = (nid >> 1) * 128;
    const int fblk = nid & 1;

    const char* a_base[2];
    const char* b_base[2];
#pragma unroll
    for (int q = 0; q < 2; ++q) {
        int idx = q * 256 + t;
        int chunk = idx >> 7, rnn = idx & 127;
        int m = m0 + rnn; if (m >= MTOT) m = MTOT - 1;
        int b = m / (OH * OW); int rr = m - b * (OH * OW);
        int oi = rr / OW, oj = rr - oi * OW;
        long pix = ((long)(b * H_ + oi) * W_ + oj) * CIN;  // element index
        a_base[q] = (const char*)xin + (PREBIN ? (pix + chunk * 16)       // 1 B/elem
                                               : (pix + chunk * 16) * 4); // 4 B/elem
        b_base[q] = (const char*)wst + fblk * 8192 + idx * 16;
    }

    intx4 acc[4][4];
#pragma unroll
    for (int a = 0; a < 4; ++a)
#pragma unroll
        for (int bb = 0; bb < 4; ++bb) acc[a][bb] = (intx4){0, 0, 0, 0};

    // stage tile ks into buffer buf (4 vmcnt-counted ops/thread on PREBIN path)
    auto STAGE = [&](int ks, int buf) {
        int kh = ks / 6, rem = ks - kh * 6;
        int kw = rem >> 1, c0 = (rem & 1) << 6;
        int aoff = (kh * W_ + kw) * CIN + c0;   // element offset from pixel base
        char* dst = smem + buf * 16384;
#pragma unroll
        for (int q = 0; q < 2; ++q) {
            int idx = q * 256 + t;
            if (PREBIN) {
                gld_lds16(a_base[q] + aoff, dst + idx * 16);
            } else {
                const float4* src = (const float4*)(a_base[q] + (long)aoff * 4);
                float4 v0 = src[0], v1 = src[1], v2 = src[2], v3 = src[3];
                uint4 pv = make_uint4(pack4sign(v0), pack4sign(v1),
                                      pack4sign(v2), pack4sign(v3));
                *(uint4*)(dst + idx * 16) = pv;
            }
            gld_lds16(b_base[q] + (long)ks * 16384, dst + 8192 + idx * 16);
        }
    };

    STAGE(0, 0);   // prologue: 4 loads in flight

    for (int ks = 0; ks < 18; ++ks) {
        const int cur = ks & 1;
        // issue next-tile prefetch, then wait ONLY for current tile's loads
        if (ks < 17) {
            STAGE(ks + 1, cur ^ 1);
            if (PREBIN)
                asm volatile("s_waitcnt vmcnt(4)\ns_barrier" ::: "memory");
            else
                __syncthreads();   // fallback path: full drain (ds_write visibility)
        } else {
            if (PREBIN)
                asm volatile("s_waitcnt vmcnt(0)\ns_barrier" ::: "memory");
            else
                __syncthreads();
        }

        const char* sbase = smem + cur * 16384;
        intx4 af[4], bf[4];
#pragma unroll
        for (int tm = 0; tm < 4; ++tm) {
            int row = wm * 64 + tm * 16 + lane16;
            af[tm] = *(const intx4*)(sbase + quad * 2048 + row * 16);
        }
#pragma unroll
        for (int tn = 0; tn < 4; ++tn) {
            int col = wn * 64 + tn * 16 + lane16;
            bf[tn] = *(const intx4*)(sbase + 8192 + quad * 2048 + col * 16);
        }
        __builtin_amdgcn_s_setprio(1);
#pragma unroll
        for (int tm = 0; tm < 4; ++tm)
#pragma unroll
            for (int tn = 0; tn < 4; ++tn)
                acc[tm][tn] = __builtin_amdgcn_mfma_i32_16x16x64_i8(
                    af[tm], bf[tn], acc[tm][tn], 0, 0, 0);
        __builtin_amdgcn_s_setprio(0);
        // all waves done READING buf[cur] before anyone overwrites it (ks+2 stage)
        asm volatile("s_barrier" ::: "memory");
    }

    // epilogue: out[m,f] = beta[m] * sf[f] * acc
    float sv[4];
#pragma unroll
    for (int tn = 0; tn < 4; ++tn) sv[tn] = sf[f0 + wn * 64 + tn * 16 + lane16];

#pragma unroll
    for (int tm = 0; tm < 4; ++tm) {
#pragma unroll
        for (int i = 0; i < 4; ++i) {
            int m = m0 + wm * 64 + tm * 16 + quad * 4 + i;
            if (m < MTOT) {
                float bv = beta[m];
                float* op = out + (long)m * F_ + f0 + wn * 64 + lane16;
#pragma unroll
                for (int tn = 0; tn < 4; ++tn)
                    op[tn * 16] = (float)acc[tm][tn][i] * (bv * sv[tn]);
            }
        }
    }
}

extern "C" void kernel_launch(void* const* d_in, const int* in_sizes, int n_in,
                              void* d_out, int out_size, void* d_ws, size_t ws_size,
                              hipStream_t stream) {
    const float* x    = (const float*)d_in[0];
    const float* kern = (const float*)d_in[1];
    const float* alph = (const float*)d_in[2];
    float* out = (float*)d_out;
    char* ws = (char*)d_ws;

    int8_t* wst  = (int8_t*)(ws + WST_OFF);
    float*  sf   = (float*)(ws + SF_OFF);
    float*  S    = (float*)(ws + S_OFF);
    float*  beta = (float*)(ws + BETA_OFF);
    char*   xq   = ws + XQ_OFF;
    bool prebin = ws_size >= NEED_FULL;

    hipLaunchKernelGGL(prep_wq, dim3(KTOT * F_ / 256), dim3(256), 0, stream,
                       kern, alph, wst, sf);
    hipLaunchKernelGGL(prep_x, dim3(PIX_IN * CIN / 4 / 256), dim3(256), 0, stream,
                       x, (uint32_t*)xq, S, (int)prebin);
    hipLaunchKernelGGL(prep_beta, dim3((MTOT + 255) / 256), dim3(256), 0, stream, S, beta);

    dim3 grid(2, (MTOT + 127) / 128);  // f-halves x m-tiles
    if (prebin)
        hipLaunchKernelGGL(conv_main<true>, grid, dim3(256), 0, stream,
                           (const void*)xq, wst, sf, beta, out);
    else
        hipLaunchKernelGGL(conv_main<false>, grid, dim3(256), 0, stream,
                           (const void*)x, wst, sf, beta, out);
}

// Round 2
// 325.979 us; speedup vs baseline: 1.0810x; 1.0283x over previous
//
#include <hip/hip_runtime.h>
#include <hip/hip_bf16.h>
#include <stdint.h>

// Problem constants
#define B_   16
#define H_   112
#define W_   112
#define CIN  128
#define F_   256
#define OH   110
#define OW   110
#define MTOT (B_*OH*OW)        // 193600 output pixels
#define KTOT 1152              // 3*3*128
#define PIX_IN (B_*H_*W_)      // 200704 input pixels
#define D_INV (1.0f/1152.0f)

typedef float floatx4 __attribute__((ext_vector_type(4)));
typedef int   intx4   __attribute__((ext_vector_type(4)));

typedef __attribute__((address_space(1))) uint32_t guint;
typedef __attribute__((address_space(3))) uint32_t luint;

__device__ __forceinline__ void gld_lds16(const void* g, void* l) {
    __builtin_amdgcn_global_load_lds((guint*)g, (luint*)l, 16, 0, 0);
}

// ws layout (bytes):
//   wst  i8   [18 ks][2 fh][4 chunk][128 n][16 j]  = 294912
//   sf   f32  [256]                                = 1024
//   S    f32  [PIX_IN]                             = 802816
//   beta f32  [MTOT]                               = 774400
//   xq   i8   CHUNK-MAJOR [8 chunk][PIX_IN][16B]   = 25690112
#define WST_OFF   0
#define SF_OFF    294912
#define S_OFF     295936
#define BETA_OFF  1098752
#define XQ_OFF    1873152
#define NEED_FULL (XQ_OFF + (size_t)PIX_IN*CIN)

// ---- prep: W' = sum_e alpha[e,f]*sign(K_e); quantize i8 with s_f ----------
__global__ void prep_wq(const float* __restrict__ kern, const float* __restrict__ alph,
                        int8_t* __restrict__ wst, float* __restrict__ sf) {
    int idx = blockIdx.x * 256 + threadIdx.x;   // = r*256 + f
    int r = idx >> 8, f = idx & 255;
    float a0 = alph[f], a1 = alph[256 + f], a2 = alph[512 + f];  // >= 0
    float w = 0.f;
    float kv0 = kern[idx], kv1 = kern[294912 + idx], kv2 = kern[589824 + idx];
    w += (__float_as_uint(kv0) & 0x80000000u) ? -a0 : a0;
    w += (__float_as_uint(kv1) & 0x80000000u) ? -a1 : a1;
    w += (__float_as_uint(kv2) & 0x80000000u) ? -a2 : a2;
    float s = (a0 + a1 + a2) * (1.0f / 127.0f);          // bounds |w| -> |q|<=127
    int q = (int)__builtin_rintf(w / s);
    // image addr: [ks=r>>6][fh=f>>7][chunk=(r>>4)&3][n=f&127][j=r&15]
    wst[((((r >> 6) * 2 + (f >> 7)) * 4 + ((r >> 4) & 3)) * 128 + (f & 127)) * 16 + (r & 15)]
        = (int8_t)q;
    if (r == 0) sf[f] = s;
}

// ---- prep: binarize x -> xq (i8 +-1, CHUNK-MAJOR), per-pixel sum|x| -------
__device__ __forceinline__ uint32_t pack4sign(float4 v) {
    uint32_t b0 = ((__float_as_uint(v.x) >> 31) * 0xFEu) ^ 0x01u;
    uint32_t b1 = ((__float_as_uint(v.y) >> 31) * 0xFEu) ^ 0x01u;
    uint32_t b2 = ((__float_as_uint(v.z) >> 31) * 0xFEu) ^ 0x01u;
    uint32_t b3 = ((__float_as_uint(v.w) >> 31) * 0xFEu) ^ 0x01u;
    return b0 | (b1 << 8) | (b2 << 16) | (b3 << 24);
}

__global__ void prep_x(const float* __restrict__ x, uint32_t* __restrict__ xq,
                       float* __restrict__ S, int write_xq) {
    int idx = blockIdx.x * 256 + threadIdx.x;   // float4 index; 32 per pixel
    float4 v = ((const float4*)x)[idx];
    if (write_xq) {
        // chunk-major: [chunk=sub>>2][pix][word=sub&3]
        int pix = idx >> 5, sub = idx & 31;
        xq[((sub >> 2) * (long)PIX_IN + pix) * 4 + (sub & 3)] = pack4sign(v);
    }
    float s = fabsf(v.x) + fabsf(v.y) + fabsf(v.z) + fabsf(v.w);
#pragma unroll
    for (int o = 1; o < 32; o <<= 1) s += __shfl_xor(s, o, 64);  // within 32-group
    if ((threadIdx.x & 31) == 0) S[idx >> 5] = s;
}

// ---- prep: beta = 3x3 box of S / 1152 -------------------------------------
__global__ void prep_beta(const float* __restrict__ S, float* __restrict__ beta) {
    int m = blockIdx.x * 256 + threadIdx.x;
    if (m >= MTOT) return;
    int b = m / (OH * OW); int r = m - b * (OH * OW);
    int oi = r / OW, oj = r - oi * OW;
    const float* sp = S + (b * H_ + oi) * W_ + oj;
    float acc = 0.f;
#pragma unroll
    for (int dh = 0; dh < 3; ++dh)
#pragma unroll
        for (int dw = 0; dw < 3; ++dw) acc += sp[dh * W_ + dw];
    beta[m] = acc * D_INV;
}

// ---- main: implicit GEMM, 128x128 tile, 16x16x64 i8 MFMA, BK=64 -----------
// v3: chunk-major xq -> coalesced A-staging (contiguous 1KB per wave-instr),
//     double-buffered LDS + 1-step prefetch with counted vmcnt(4),
//     bijective XCD-aware block swizzle, setprio around MFMA cluster.
template <bool PREBIN>
__global__ __launch_bounds__(256)
void conv_main(const void* __restrict__ xin, const int8_t* __restrict__ wst,
               const float* __restrict__ sf, const float* __restrict__ beta,
               float* __restrict__ out) {
    // two buffers of 16 KB: each {A: [4 chunk(k16)][128 row][16B]; B at +8192}
    __shared__ char smem[32768];

    const int t = threadIdx.x;
    const int l = t & 63, wv = t >> 6;
    const int quad = l >> 4, lane16 = l & 15;
    const int wm = wv >> 1, wn = wv & 1;

    // --- bijective XCD swizzle (m204): contiguous logical ids per XCD ---
    const int nwg  = gridDim.x * gridDim.y;            // 3026
    const int wgid = blockIdx.y * gridDim.x + blockIdx.x;
    const int qn = nwg >> 3, rn = nwg & 7;
    const int xcd = wgid & 7, ii = wgid >> 3;
    const int nid = (xcd < rn ? xcd * (qn + 1) : rn * (qn + 1) + (xcd - rn) * qn) + ii;
    const int f0 = (nid & 1) * 128;     // f-halves of same m-tile adjacent -> same XCD
    const int m0 = (nid >> 1) * 128;
    const int fblk = nid & 1;

    const char* a_base[2];
    const char* b_base[2];
#pragma unroll
    for (int q = 0; q < 2; ++q) {
        int idx = q * 256 + t;
        int chunk = idx >> 7, rnn = idx & 127;
        int m = m0 + rnn; if (m >= MTOT) m = MTOT - 1;
        int b = m / (OH * OW); int rr = m - b * (OH * OW);
        int oi = rr / OW, oj = rr - oi * OW;
        long pix = (long)(b * H_ + oi) * W_ + oj;          // PIXEL index
        // PREBIN: chunk-major xq -> [chunk][pix][16B]; rows of a chunk contiguous
        a_base[q] = (const char*)xin +
                    (PREBIN ? ((long)chunk * PIX_IN + pix) * 16
                            : (pix * CIN + chunk * 16) * 4);
        b_base[q] = (const char*)wst + fblk * 8192 + idx * 16;
    }

    intx4 acc[4][4];
#pragma unroll
    for (int a = 0; a < 4; ++a)
#pragma unroll
        for (int bb = 0; bb < 4; ++bb) acc[a][bb] = (intx4){0, 0, 0, 0};

    // stage tile ks into buffer buf (4 vmcnt-counted ops/thread on PREBIN path)
    auto STAGE = [&](int ks, int buf) {
        int kh = ks / 6, rem = ks - kh * 6;
        int kw = rem >> 1, c0sel = rem & 1;                // c0 = c0sel*64
        char* dst = smem + buf * 16384;
        // PREBIN byte offset: +4 chunk regions if upper channel half, + pixel shift
        long aoffP = ((long)c0sel * 4 * PIX_IN + (kh * W_ + kw)) * 16;
        long aoffF = ((long)(kh * W_ + kw) * CIN + (c0sel << 6)) * 4;
#pragma unroll
        for (int q = 0; q < 2; ++q) {
            int idx = q * 256 + t;
            if (PREBIN) {
                gld_lds16(a_base[q] + aoffP, dst + idx * 16);
            } else {
                const float4* src = (const float4*)(a_base[q] + aoffF);
                float4 v0 = src[0], v1 = src[1], v2 = src[2], v3 = src[3];
                uint4 pv = make_uint4(pack4sign(v0), pack4sign(v1),
                                      pack4sign(v2), pack4sign(v3));
                *(uint4*)(dst + idx * 16) = pv;
            }
            gld_lds16(b_base[q] + (long)ks * 16384, dst + 8192 + idx * 16);
        }
    };

    STAGE(0, 0);   // prologue: 4 loads in flight

    for (int ks = 0; ks < 18; ++ks) {
        const int cur = ks & 1;
        // issue next-tile prefetch, then wait ONLY for current tile's loads
        if (ks < 17) {
            STAGE(ks + 1, cur ^ 1);
            if (PREBIN)
                asm volatile("s_waitcnt vmcnt(4)\ns_barrier" ::: "memory");
            else
                __syncthreads();   // fallback path: full drain (ds_write visibility)
        } else {
            if (PREBIN)
                asm volatile("s_waitcnt vmcnt(0)\ns_barrier" ::: "memory");
            else
                __syncthreads();
        }

        const char* sbase = smem + cur * 16384;
        intx4 af[4], bf[4];
#pragma unroll
        for (int tm = 0; tm < 4; ++tm) {
            int row = wm * 64 + tm * 16 + lane16;
            af[tm] = *(const intx4*)(sbase + quad * 2048 + row * 16);
        }
#pragma unroll
        for (int tn = 0; tn < 4; ++tn) {
            int col = wn * 64 + tn * 16 + lane16;
            bf[tn] = *(const intx4*)(sbase + 8192 + quad * 2048 + col * 16);
        }
        __builtin_amdgcn_s_setprio(1);
#pragma unroll
        for (int tm = 0; tm < 4; ++tm)
#pragma unroll
            for (int tn = 0; tn < 4; ++tn)
                acc[tm][tn] = __builtin_amdgcn_mfma_i32_16x16x64_i8(
                    af[tm], bf[tn], acc[tm][tn], 0, 0, 0);
        __builtin_amdgcn_s_setprio(0);
        // all waves done READING buf[cur] before anyone overwrites it (ks+2 stage)
        asm volatile("s_barrier" ::: "memory");
    }

    // epilogue: out[m,f] = beta[m] * sf[f] * acc
    float sv[4];
#pragma unroll
    for (int tn = 0; tn < 4; ++tn) sv[tn] = sf[f0 + wn * 64 + tn * 16 + lane16];

#pragma unroll
    for (int tm = 0; tm < 4; ++tm) {
#pragma unroll
        for (int i = 0; i < 4; ++i) {
            int m = m0 + wm * 64 + tm * 16 + quad * 4 + i;
            if (m < MTOT) {
                float bv = beta[m];
                float* op = out + (long)m * F_ + f0 + wn * 64 + lane16;
#pragma unroll
                for (int tn = 0; tn < 4; ++tn)
                    op[tn * 16] = (float)acc[tm][tn][i] * (bv * sv[tn]);
            }
        }
    }
}

extern "C" void kernel_launch(void* const* d_in, const int* in_sizes, int n_in,
                              void* d_out, int out_size, void* d_ws, size_t ws_size,
                              hipStream_t stream) {
    const float* x    = (const float*)d_in[0];
    const float* kern = (const float*)d_in[1];
    const float* alph = (const float*)d_in[2];
    float* out = (float*)d_out;
    char* ws = (char*)d_ws;

    int8_t* wst  = (int8_t*)(ws + WST_OFF);
    float*  sf   = (float*)(ws + SF_OFF);
    float*  S    = (float*)(ws + S_OFF);
    float*  beta = (float*)(ws + BETA_OFF);
    char*   xq   = ws + XQ_OFF;
    bool prebin = ws_size >= NEED_FULL;

    hipLaunchKernelGGL(prep_wq, dim3(KTOT * F_ / 256), dim3(256), 0, stream,
                       kern, alph, wst, sf);
    hipLaunchKernelGGL(prep_x, dim3(PIX_IN * CIN / 4 / 256), dim3(256), 0, stream,
                       x, (uint32_t*)xq, S, (int)prebin);
    hipLaunchKernelGGL(prep_beta, dim3((MTOT + 255) / 256), dim3(256), 0, stream, S, beta);

    dim3 grid(2, (MTOT + 127) / 128);  // f-halves x m-tiles
    if (prebin)
        hipLaunchKernelGGL(conv_main<true>, grid, dim3(256), 0, stream,
                           (const void*)xq, wst, sf, beta, out);
    else
        hipLaunchKernelGGL(conv_main<false>, grid, dim3(256), 0, stream,
                           (const void*)x, wst, sf, beta, out);
}

// Round 3
// 320.775 us; speedup vs baseline: 1.0985x; 1.0162x over previous
//
#include <hip/hip_runtime.h>
#include <hip/hip_bf16.h>
#include <stdint.h>

// Problem constants
#define B_   16
#define H_   112
#define W_   112
#define CIN  128
#define F_   256
#define OH   110
#define OW   110
#define MTOT (B_*OH*OW)        // 193600 output pixels
#define KTOT 1152              // 3*3*128
#define PIX_IN (B_*H_*W_)      // 200704 input pixels
#define D_INV (1.0f/1152.0f)

typedef float floatx4 __attribute__((ext_vector_type(4)));
typedef int   intx4   __attribute__((ext_vector_type(4)));

typedef __attribute__((address_space(1))) uint32_t guint;
typedef __attribute__((address_space(3))) uint32_t luint;

__device__ __forceinline__ void gld_lds16(const void* g, void* l) {
    __builtin_amdgcn_global_load_lds((guint*)g, (luint*)l, 16, 0, 0);
}

// ws layout (bytes):
//   wst  i8   [18 ks][2 fh][4 chunk][128 n][16 j]  = 294912
//   sf   f32  [256]                                = 1024
//   S    f32  [PIX_IN]                             = 802816
//   beta f32  [MTOT]                               = 774400
//   xq   i8   CHUNK-MAJOR [8 chunk][PIX_IN][16B]   = 25690112
#define WST_OFF   0
#define SF_OFF    294912
#define S_OFF     295936
#define BETA_OFF  1098752
#define XQ_OFF    1873152
#define NEED_FULL (XQ_OFF + (size_t)PIX_IN*CIN)

// ---- prep: W' = sum_e alpha[e,f]*sign(K_e); quantize i8 with s_f ----------
__global__ void prep_wq(const float* __restrict__ kern, const float* __restrict__ alph,
                        int8_t* __restrict__ wst, float* __restrict__ sf) {
    int idx = blockIdx.x * 256 + threadIdx.x;   // = r*256 + f
    int r = idx >> 8, f = idx & 255;
    float a0 = alph[f], a1 = alph[256 + f], a2 = alph[512 + f];  // >= 0
    float w = 0.f;
    float kv0 = kern[idx], kv1 = kern[294912 + idx], kv2 = kern[589824 + idx];
    w += (__float_as_uint(kv0) & 0x80000000u) ? -a0 : a0;
    w += (__float_as_uint(kv1) & 0x80000000u) ? -a1 : a1;
    w += (__float_as_uint(kv2) & 0x80000000u) ? -a2 : a2;
    float s = (a0 + a1 + a2) * (1.0f / 127.0f);          // bounds |w| -> |q|<=127
    int q = (int)__builtin_rintf(w / s);
    // image addr: [ks=r>>6][fh=f>>7][chunk=(r>>4)&3][n=f&127][j=r&15]
    wst[((((r >> 6) * 2 + (f >> 7)) * 4 + ((r >> 4) & 3)) * 128 + (f & 127)) * 16 + (r & 15)]
        = (int8_t)q;
    if (r == 0) sf[f] = s;
}

// ---- prep: binarize x -> xq (i8 +-1, CHUNK-MAJOR), per-pixel sum|x| -------
__device__ __forceinline__ uint32_t pack4sign(float4 v) {
    uint32_t b0 = ((__float_as_uint(v.x) >> 31) * 0xFEu) ^ 0x01u;
    uint32_t b1 = ((__float_as_uint(v.y) >> 31) * 0xFEu) ^ 0x01u;
    uint32_t b2 = ((__float_as_uint(v.z) >> 31) * 0xFEu) ^ 0x01u;
    uint32_t b3 = ((__float_as_uint(v.w) >> 31) * 0xFEu) ^ 0x01u;
    return b0 | (b1 << 8) | (b2 << 16) | (b3 << 24);
}

__global__ void prep_x(const float* __restrict__ x, uint32_t* __restrict__ xq,
                       float* __restrict__ S, int write_xq) {
    int idx = blockIdx.x * 256 + threadIdx.x;   // float4 index; 32 per pixel
    float4 v = ((const float4*)x)[idx];
    if (write_xq) {
        // chunk-major: [chunk=sub>>2][pix][word=sub&3]
        int pix = idx >> 5, sub = idx & 31;
        xq[((sub >> 2) * (long)PIX_IN + pix) * 4 + (sub & 3)] = pack4sign(v);
    }
    float s = fabsf(v.x) + fabsf(v.y) + fabsf(v.z) + fabsf(v.w);
#pragma unroll
    for (int o = 1; o < 32; o <<= 1) s += __shfl_xor(s, o, 64);  // within 32-group
    if ((threadIdx.x & 31) == 0) S[idx >> 5] = s;
}

// ---- prep: beta = 3x3 box of S / 1152 -------------------------------------
__global__ void prep_beta(const float* __restrict__ S, float* __restrict__ beta) {
    int m = blockIdx.x * 256 + threadIdx.x;
    if (m >= MTOT) return;
    int b = m / (OH * OW); int r = m - b * (OH * OW);
    int oi = r / OW, oj = r - oi * OW;
    const float* sp = S + (b * H_ + oi) * W_ + oj;
    float acc = 0.f;
#pragma unroll
    for (int dh = 0; dh < 3; ++dh)
#pragma unroll
        for (int dw = 0; dw < 3; ++dw) acc += sp[dh * W_ + dw];
    beta[m] = acc * D_INV;
}

// ---- main: implicit GEMM, 128x256 tile, 512 thr, 16x16x64 i8 MFMA, BK=64 --
// v4: fused f-halves -> one block computes all 256 filters for a 128-row
//     m-tile (A staged ONCE, was twice); 8 waves (2m x 4n); dbuf LDS 2x24KB;
//     counted vmcnt(3); bijective XCD swizzle; setprio around MFMA.
template <bool PREBIN>
__global__ __launch_bounds__(512, 4)
void conv_main(const void* __restrict__ xin, const int8_t* __restrict__ wst,
               const float* __restrict__ sf, const float* __restrict__ beta,
               float* __restrict__ out) {
    // per buffer: A [4 chunk][128 row][16B] = 8 KB ; B [2 fh][4 chunk][128 col][16B] = 16 KB
    __shared__ char smem[49152];

    const int t = threadIdx.x;
    const int l = t & 63, wv = t >> 6;             // wv 0..7
    const int quad = l >> 4, lane16 = l & 15;
    const int wm = wv >> 2, wn = wv & 3;           // 2m x 4n wave grid

    // --- bijective XCD swizzle (m204): contiguous logical ids per XCD ---
    const int nwg  = gridDim.x;                    // 1513
    const int wgid = blockIdx.x;
    const int qn = nwg >> 3, rn = nwg & 7;
    const int xcd = wgid & 7, ii = wgid >> 3;
    const int nid = (xcd < rn ? xcd * (qn + 1) : rn * (qn + 1) + (xcd - rn) * qn) + ii;
    const int m0 = nid * 128;

    // A staging address: thread t handles chunk=t>>7, row=t&127 (one 16B slot)
    const char* a_base;
    {
        int chunk = t >> 7, rnn = t & 127;
        int m = m0 + rnn; if (m >= MTOT) m = MTOT - 1;
        int b = m / (OH * OW); int rr = m - b * (OH * OW);
        int oi = rr / OW, oj = rr - oi * OW;
        long pix = (long)(b * H_ + oi) * W_ + oj;          // PIXEL index
        a_base = (const char*)xin +
                 (PREBIN ? ((long)chunk * PIX_IN + pix) * 16
                         : (pix * CIN + chunk * 16) * 4);
    }
    // B staging: two 16B slots/thread, idx2 = q*512+t over 16 KB (both fh)
    const char* b_base = (const char*)wst + (long)t * 16;

    intx4 acc[4][4];
#pragma unroll
    for (int a = 0; a < 4; ++a)
#pragma unroll
        for (int bb = 0; bb < 4; ++bb) acc[a][bb] = (intx4){0, 0, 0, 0};

    // stage tile ks into buffer buf (3 vmcnt-counted ops/thread on PREBIN path)
    auto STAGE = [&](int ks, int buf) {
        int kh = ks / 6, rem = ks - kh * 6;
        int kw = rem >> 1, c0sel = rem & 1;                // c0 = c0sel*64
        char* dst = smem + buf * 24576;
        long aoffP = ((long)c0sel * 4 * PIX_IN + (kh * W_ + kw)) * 16;
        long aoffF = ((long)(kh * W_ + kw) * CIN + (c0sel << 6)) * 4;
        if (PREBIN) {
            gld_lds16(a_base + aoffP, dst + t * 16);
        } else {
            const float4* src = (const float4*)(a_base + aoffF);
            float4 v0 = src[0], v1 = src[1], v2 = src[2], v3 = src[3];
            uint4 pv = make_uint4(pack4sign(v0), pack4sign(v1),
                                  pack4sign(v2), pack4sign(v3));
            *(uint4*)(dst + t * 16) = pv;
        }
#pragma unroll
        for (int q = 0; q < 2; ++q) {
            long idx2 = q * 512 + t;
            gld_lds16(b_base + q * 8192 + (long)ks * 16384, dst + 8192 + idx2 * 16);
        }
    };

    STAGE(0, 0);   // prologue: 3 loads in flight

    for (int ks = 0; ks < 18; ++ks) {
        const int cur = ks & 1;
        // issue next-tile prefetch, then wait ONLY for current tile's loads
        if (ks < 17) {
            STAGE(ks + 1, cur ^ 1);
            if (PREBIN)
                asm volatile("s_waitcnt vmcnt(3)\ns_barrier" ::: "memory");
            else
                __syncthreads();   // fallback path: full drain (ds_write visibility)
        } else {
            if (PREBIN)
                asm volatile("s_waitcnt vmcnt(0)\ns_barrier" ::: "memory");
            else
                __syncthreads();
        }

        const char* sbase = smem + cur * 24576;
        intx4 af[4], bf[4];
#pragma unroll
        for (int tm = 0; tm < 4; ++tm) {
            int row = wm * 64 + tm * 16 + lane16;
            af[tm] = *(const intx4*)(sbase + quad * 2048 + row * 16);
        }
#pragma unroll
        for (int tn = 0; tn < 4; ++tn) {
            // B LDS: [fh=wn>>1][chunk=quad][col128=(wn&1)*64+tn*16+lane16][16B]
            int col = (wn & 1) * 64 + tn * 16 + lane16;
            bf[tn] = *(const intx4*)(sbase + 8192 + (wn >> 1) * 8192
                                     + quad * 2048 + col * 16);
        }
        __builtin_amdgcn_s_setprio(1);
#pragma unroll
        for (int tm = 0; tm < 4; ++tm)
#pragma unroll
            for (int tn = 0; tn < 4; ++tn)
                acc[tm][tn] = __builtin_amdgcn_mfma_i32_16x16x64_i8(
                    af[tm], bf[tn], acc[tm][tn], 0, 0, 0);
        __builtin_amdgcn_s_setprio(0);
        // all waves done READING buf[cur] before anyone overwrites it (ks+2 stage)
        asm volatile("s_barrier" ::: "memory");
    }

    // epilogue: out[m,f] = beta[m] * sf[f] * acc ; global f = wn*64+tn*16+lane16
    float sv[4];
#pragma unroll
    for (int tn = 0; tn < 4; ++tn) sv[tn] = sf[wn * 64 + tn * 16 + lane16];

#pragma unroll
    for (int tm = 0; tm < 4; ++tm) {
#pragma unroll
        for (int i = 0; i < 4; ++i) {
            int m = m0 + wm * 64 + tm * 16 + quad * 4 + i;
            if (m < MTOT) {
                float bv = beta[m];
                float* op = out + (long)m * F_ + wn * 64 + lane16;
#pragma unroll
                for (int tn = 0; tn < 4; ++tn)
                    op[tn * 16] = (float)acc[tm][tn][i] * (bv * sv[tn]);
            }
        }
    }
}

extern "C" void kernel_launch(void* const* d_in, const int* in_sizes, int n_in,
                              void* d_out, int out_size, void* d_ws, size_t ws_size,
                              hipStream_t stream) {
    const float* x    = (const float*)d_in[0];
    const float* kern = (const float*)d_in[1];
    const float* alph = (const float*)d_in[2];
    float* out = (float*)d_out;
    char* ws = (char*)d_ws;

    int8_t* wst  = (int8_t*)(ws + WST_OFF);
    float*  sf   = (float*)(ws + SF_OFF);
    float*  S    = (float*)(ws + S_OFF);
    float*  beta = (float*)(ws + BETA_OFF);
    char*   xq   = ws + XQ_OFF;
    bool prebin = ws_size >= NEED_FULL;

    hipLaunchKernelGGL(prep_wq, dim3(KTOT * F_ / 256), dim3(256), 0, stream,
                       kern, alph, wst, sf);
    hipLaunchKernelGGL(prep_x, dim3(PIX_IN * CIN / 4 / 256), dim3(256), 0, stream,
                       x, (uint32_t*)xq, S, (int)prebin);
    hipLaunchKernelGGL(prep_beta, dim3((MTOT + 255) / 256), dim3(256), 0, stream, S, beta);

    dim3 grid((MTOT + 127) / 128);   // one block per 128-row m-tile, all 256 f
    if (prebin)
        hipLaunchKernelGGL(conv_main<true>, grid, dim3(512), 0, stream,
                           (const void*)xq, wst, sf, beta, out);
    else
        hipLaunchKernelGGL(conv_main<false>, grid, dim3(512), 0, stream,
                           (const void*)x, wst, sf, beta, out);
}